// Round 4
// baseline (1119.175 us; speedup 1.0000x reference)
//
#include <hip/hip_runtime.h>
#include <math.h>

#define TT   512
#define BB   64
#define EMBD 512
#define HIDD 512

typedef _Float16 half2v __attribute__((ext_vector_type(2)));

__device__ __forceinline__ float fdot2(unsigned a, unsigned b, float c) {
  half2v av = __builtin_bit_cast(half2v, a);
  half2v bv = __builtin_bit_cast(half2v, b);
#if __has_builtin(__builtin_amdgcn_fdot2)
  return __builtin_amdgcn_fdot2(av, bv, c, false);
#else
  return c + (float)av.x * (float)bv.x + (float)av.y * (float)bv.y;
#endif
}

// ---------------------------------------------------------------------------
// K0: repack fp32 W1h (W1[j][512..1024)) -> fp16, layout wp[c][tid512]:
// tid -> (seg = tid>>8, jb = tid&255); chunk c = 2*kq+jj covers
// j = 2*jb+jj, k = 256*seg + 8*kq .. +8   (kq 0..31, jj 0..1).
// 64 chunks x 512 threads x 16B = 512 KB. Every K2 load is lane-coalesced.
// ---------------------------------------------------------------------------
__global__ __launch_bounds__(256) void repack_w1h(
    const float* __restrict__ W1, uint4* __restrict__ wp)
{
  const int gid = blockIdx.x * 256 + threadIdx.x;   // 0..32767
  const int c   = gid >> 9;                         // 0..63
  const int tid = gid & 511;
  const int jj = c & 1, kq = c >> 1;
  const int seg = tid >> 8, jb = tid & 255;
  const int j = 2 * jb + jj;
  const float* src = W1 + (size_t)j * (2 * EMBD) + EMBD + seg * 256 + 8 * kq;
  unsigned r[4];
#pragma unroll
  for (int q = 0; q < 4; q++) {
    half2v hv;
    hv.x = (_Float16)src[2 * q];
    hv.y = (_Float16)src[2 * q + 1];
    r[q] = __builtin_bit_cast(unsigned, hv);
  }
  uint4 u; u.x = r[0]; u.y = r[1]; u.z = r[2]; u.w = r[3];
  wp[gid] = u;
}

// ---------------------------------------------------------------------------
// K1: px[m][j] = b1[j] + sum_k emb[x[m]][k] * W1[j][k]  (fp32 tile GEMM)
// ---------------------------------------------------------------------------
__global__ __launch_bounds__(256) void px_gemm(
    const int* __restrict__ x, const float* __restrict__ emb,
    const float* __restrict__ W1, const float* __restrict__ b1,
    float* __restrict__ px)
{
  __shared__ float As[8][132];
  __shared__ float Bs[8][132];
  __shared__ int stok[128];
  const int tid = threadIdx.x;
  const int m0 = blockIdx.x * 128;
  const int j0 = blockIdx.y * 128;
  if (tid < 128) stok[tid] = x[m0 + tid];
  __syncthreads();
  const int lr = tid >> 1;
  const int lh = (tid & 1) * 4;
  const int ty = tid >> 4, tx = tid & 15;
  const size_t arow = (size_t)stok[lr] * EMBD;
  const float* brow = W1 + (size_t)(j0 + lr) * (2 * EMBD);

  float acc[8][8];
#pragma unroll
  for (int i = 0; i < 8; i++)
#pragma unroll
    for (int q = 0; q < 8; q++) acc[i][q] = 0.f;

  for (int k0 = 0; k0 < EMBD; k0 += 8) {
    float4 av = *(const float4*)(emb + arow + k0 + lh);
    float4 bv = *(const float4*)(brow + k0 + lh);
    __syncthreads();
    As[lh + 0][lr] = av.x; As[lh + 1][lr] = av.y; As[lh + 2][lr] = av.z; As[lh + 3][lr] = av.w;
    Bs[lh + 0][lr] = bv.x; Bs[lh + 1][lr] = bv.y; Bs[lh + 2][lr] = bv.z; Bs[lh + 3][lr] = bv.w;
    __syncthreads();
#pragma unroll
    for (int kk = 0; kk < 8; kk++) {
      float4 a0 = *(const float4*)&As[kk][ty * 8];
      float4 a1 = *(const float4*)&As[kk][ty * 8 + 4];
      float4 c0 = *(const float4*)&Bs[kk][tx * 8];
      float4 c1 = *(const float4*)&Bs[kk][tx * 8 + 4];
      float a[8] = {a0.x,a0.y,a0.z,a0.w,a1.x,a1.y,a1.z,a1.w};
      float bb[8] = {c0.x,c0.y,c0.z,c0.w,c1.x,c1.y,c1.z,c1.w};
#pragma unroll
      for (int i = 0; i < 8; i++)
#pragma unroll
        for (int q = 0; q < 8; q++)
          acc[i][q] = fmaf(a[i], bb[q], acc[i][q]);
    }
  }
  const float* bp = b1 + j0 + tx * 8;
  float bias0[8];
#pragma unroll
  for (int q = 0; q < 8; q++) bias0[q] = bp[q];
#pragma unroll
  for (int i = 0; i < 8; i++) {
    float o[8];
#pragma unroll
    for (int q = 0; q < 8; q++) o[q] = acc[i][q] + bias0[q];
    float* dst = px + (size_t)(m0 + ty * 8 + i) * HIDD + j0 + tx * 8;
    *(float4*)dst       = make_float4(o[0], o[1], o[2], o[3]);
    *(float4*)(dst + 4) = make_float4(o[4], o[5], o[6], o[7]);
  }
}

// ---------------------------------------------------------------------------
// K2: recurrence. 64 wgs x 512 threads (8 waves, __launch_bounds__(512,2)
// -> 256-VGPR cap). Thread (seg=tid>>8, jb=tid&255) computes j={2jb,2jb+1}
// over k-half [256seg,256seg+256). Weights: 44 uint4 in VGPR, 6 in LDS
// (48KB dyn), 14 streamed from L2 (512KB wp is L2-resident). h broadcast
// via wave-uniform ds_read_b128. 2 barriers/step, no inter-wg traffic.
// ---------------------------------------------------------------------------
__global__ __launch_bounds__(512, 2) void elman_rec(
    const uint4* __restrict__ wp, const float* __restrict__ px,
    const float* __restrict__ W2, const float* __restrict__ b2,
    float* __restrict__ out)
{
  extern __shared__ uint4 wl[];              // 6 * 512 uint4 = 48 KB
  __shared__ __align__(16) unsigned h2[2][256];   // packed fp16 h, dbuf
  __shared__ float parts[2][HIDD];
  __shared__ float pl[HIDD];
  __shared__ float red[2][8];

  const int b   = blockIdx.x;
  const int tid = threadIdx.x;
  const int seg = tid >> 8;
  const int jb  = tid & 255;
  const int j0  = 2 * jb;

  // prologue: 44 register chunks + 6 LDS chunks (all coalesced)
  uint4 wr[44];
#pragma unroll
  for (int i = 0; i < 44; i++) wr[i] = wp[(size_t)i * 512 + tid];
#pragma unroll
  for (int i = 0; i < 6; i++) wl[i * 512 + tid] = wp[(size_t)(44 + i) * 512 + tid];
  if (tid < 256) h2[0][tid] = 0u;
  __syncthreads();

  float rm0 = -INFINITY, rm1 = -INFINITY;
  const float* pxb = px + (size_t)b * TT * HIDD;
  const uint4* wsA = wp + (size_t)50 * 512 + tid;  // chunks 50..55
  const uint4* wsB = wp + (size_t)56 * 512 + tid;  // chunks 56..63

  for (int t = 0; t < TT; t++) {
    const int cur = t & 1;

    // early issue: px for finalize threads + stream batch A
    float2 pxv = make_float2(0.f, 0.f);
    if (tid < 256) pxv = *(const float2*)(pxb + (size_t)t * HIDD + 2 * tid);
    uint4 sA[6];
#pragma unroll
    for (int i = 0; i < 6; i++) sA[i] = wsA[(size_t)i * 512];

    const uint4* hq = reinterpret_cast<const uint4*>(&h2[cur][0]) + seg * 32;
    float a0 = 0.f, c0 = 0.f, a1 = 0.f, c1 = 0.f;   // 2 chains per j

    // kq 0..21: register weights
#pragma unroll
    for (int kq = 0; kq < 22; kq++) {
      uint4 hh = hq[kq];
      uint4 w0 = wr[2 * kq], w1 = wr[2 * kq + 1];
      a0 = fdot2(w0.x, hh.x, a0); c0 = fdot2(w0.y, hh.y, c0);
      a0 = fdot2(w0.z, hh.z, a0); c0 = fdot2(w0.w, hh.w, c0);
      a1 = fdot2(w1.x, hh.x, a1); c1 = fdot2(w1.y, hh.y, c1);
      a1 = fdot2(w1.z, hh.z, a1); c1 = fdot2(w1.w, hh.w, c1);
    }
    // kq 22..24: LDS weights
#pragma unroll
    for (int kq = 22; kq < 25; kq++) {
      uint4 hh = hq[kq];
      uint4 w0 = wl[((kq - 22) * 2 + 0) * 512 + tid];
      uint4 w1 = wl[((kq - 22) * 2 + 1) * 512 + tid];
      a0 = fdot2(w0.x, hh.x, a0); c0 = fdot2(w0.y, hh.y, c0);
      a0 = fdot2(w0.z, hh.z, a0); c0 = fdot2(w0.w, hh.w, c0);
      a1 = fdot2(w1.x, hh.x, a1); c1 = fdot2(w1.y, hh.y, c1);
      a1 = fdot2(w1.z, hh.z, a1); c1 = fdot2(w1.w, hh.w, c1);
    }
    // kq 25..27: stream batch A
#pragma unroll
    for (int kq = 25; kq < 28; kq++) {
      uint4 hh = hq[kq];
      uint4 w0 = sA[(kq - 25) * 2], w1 = sA[(kq - 25) * 2 + 1];
      a0 = fdot2(w0.x, hh.x, a0); c0 = fdot2(w0.y, hh.y, c0);
      a0 = fdot2(w0.z, hh.z, a0); c0 = fdot2(w0.w, hh.w, c0);
      a1 = fdot2(w1.x, hh.x, a1); c1 = fdot2(w1.y, hh.y, c1);
      a1 = fdot2(w1.z, hh.z, a1); c1 = fdot2(w1.w, hh.w, c1);
    }
    // stream batch B (issued after A consumed: caps reg pressure)
    uint4 sB[8];
#pragma unroll
    for (int i = 0; i < 8; i++) sB[i] = wsB[(size_t)i * 512];
#pragma unroll
    for (int kq = 28; kq < 32; kq++) {
      uint4 hh = hq[kq];
      uint4 w0 = sB[(kq - 28) * 2], w1 = sB[(kq - 28) * 2 + 1];
      a0 = fdot2(w0.x, hh.x, a0); c0 = fdot2(w0.y, hh.y, c0);
      a0 = fdot2(w0.z, hh.z, a0); c0 = fdot2(w0.w, hh.w, c0);
      a1 = fdot2(w1.x, hh.x, a1); c1 = fdot2(w1.y, hh.y, c1);
      a1 = fdot2(w1.z, hh.z, a1); c1 = fdot2(w1.w, hh.w, c1);
    }

    *(float2*)&parts[seg][j0] = make_float2(a0 + c0, a1 + c1);
    __syncthreads();

    if (tid < 256) {
      float2 pA = *(const float2*)&parts[0][2 * tid];
      float2 pB = *(const float2*)&parts[1][2 * tid];
      float h0 = tanhf(pA.x + pB.x + pxv.x);
      float h1 = tanhf(pA.y + pB.y + pxv.y);
      rm0 = fmaxf(rm0, h0);
      rm1 = fmaxf(rm1, h1);
      half2v hv; hv.x = (_Float16)h0; hv.y = (_Float16)h1;
      h2[cur ^ 1][tid] = __builtin_bit_cast(unsigned, hv);
      if (t == TT - 1)
        *(float2*)(out + 2 * BB + (size_t)b * HIDD + 2 * tid) = make_float2(h0, h1);
    }
    __syncthreads();
  }

  // pooled max -> logits
  if (tid < 256) { pl[2 * tid] = rm0; pl[2 * tid + 1] = rm1; }
  __syncthreads();
  {
    float pv = pl[tid];
    float q0 = pv * W2[tid];
    float q1 = pv * W2[HIDD + tid];
#pragma unroll
    for (int off = 32; off; off >>= 1) {
      q0 += __shfl_down(q0, off);
      q1 += __shfl_down(q1, off);
    }
    const int wv = tid >> 6, ln = tid & 63;
    if (ln == 0) { red[0][wv] = q0; red[1][wv] = q1; }
  }
  __syncthreads();
  if (tid < 2) {
    float s = b2[tid];
#pragma unroll
    for (int i = 0; i < 8; i++) s += red[tid][i];
    out[b * 2 + tid] = s;
  }
}

// ---------------------------------------------------------------------------
extern "C" void kernel_launch(void* const* d_in, const int* in_sizes, int n_in,
                              void* d_out, int out_size, void* d_ws, size_t ws_size,
                              hipStream_t stream)
{
  const int*   x   = (const int*)d_in[0];
  const float* emb = (const float*)d_in[1];
  const float* W1  = (const float*)d_in[2];
  const float* b1  = (const float*)d_in[3];
  const float* W2  = (const float*)d_in[4];
  const float* b2  = (const float*)d_in[5];
  float* out = (float*)d_out;
  char* ws = (char*)d_ws;

  uint4* wp = (uint4*)ws;                        // 512 KB repacked fp16 W1h
  float* px = (float*)(ws + (1 << 19));          // 64 MB
  const size_t need = (size_t)(1 << 19) + (size_t)BB * TT * HIDD * sizeof(float);
  if (ws_size < need) return;                    // ws verified >= in prior rounds

  repack_w1h<<<128, 256, 0, stream>>>(W1, wp);
  {
    dim3 g(TT * BB / 128, HIDD / 128);           // (256, 4)
    px_gemm<<<g, 256, 0, stream>>>(x, emb, W1, b1, px);
  }

  const size_t dynBytes = 6 * 512 * sizeof(uint4);   // 48 KB (< 64 KB: no attribute needed)
  elman_rec<<<dim3(BB), dim3(512), dynBytes, stream>>>(wp, px, W2, b2, out);
}

// Round 5
// 1110.912 us; speedup vs baseline: 1.0074x; 1.0074x over previous
//
#include <hip/hip_runtime.h>
#include <math.h>

#define TT   512
#define BB   64
#define EMBD 512
#define HIDD 512

typedef _Float16 half2v __attribute__((ext_vector_type(2)));

__device__ __forceinline__ float fdot2(unsigned a, unsigned b, float c) {
  half2v av = __builtin_bit_cast(half2v, a);
  half2v bv = __builtin_bit_cast(half2v, b);
#if __has_builtin(__builtin_amdgcn_fdot2)
  return __builtin_amdgcn_fdot2(av, bv, c, false);
#else
  return c + (float)av.x * (float)bv.x + (float)av.y * (float)bv.y;
#endif
}

__device__ __forceinline__ float fast_tanh(float x) {
  // tanh(x) = 1 - 2/(1+e^{2x}); v_exp + v_rcp, ~1e-6 rel err, inf-safe.
  float e = __expf(2.0f * x);
  return 1.0f - 2.0f * __builtin_amdgcn_rcpf(e + 1.0f);
}

// ---------------------------------------------------------------------------
// K0: repack fp32 W1h -> fp16 chunks for elman_v5's mapping.
// elman thread tid: w=tid>>6, l=tid&63, qa=l>>4, jg=l&15.
// chunk c (0..63): jo=c&3, kq=c>>2. Covers j=64w+4jg+jo, k=128qa+8kq..+8
// packed as 4 dwords of (even,odd) fp16 pairs. wp[c*512+tid].
// ---------------------------------------------------------------------------
__global__ __launch_bounds__(256) void repack_w1h(
    const float* __restrict__ W1, uint4* __restrict__ wp)
{
  const int gid = blockIdx.x * 256 + threadIdx.x;   // 0..32767
  const int c   = gid >> 9;
  const int tid = gid & 511;
  const int w = tid >> 6, l = tid & 63;
  const int qa = l >> 4, jg = l & 15;
  const int jo = c & 3, kq = c >> 2;
  const int j  = 64 * w + 4 * jg + jo;
  const int k0 = 128 * qa + 8 * kq;
  const float* src = W1 + (size_t)j * (2 * EMBD) + EMBD + k0;
  unsigned r[4];
#pragma unroll
  for (int q = 0; q < 4; q++) {
    half2v hv;
    hv.x = (_Float16)src[2 * q];
    hv.y = (_Float16)src[2 * q + 1];
    r[q] = __builtin_bit_cast(unsigned, hv);
  }
  uint4 u; u.x = r[0]; u.y = r[1]; u.z = r[2]; u.w = r[3];
  wp[gid] = u;
}

// ---------------------------------------------------------------------------
// K1: px[m][j] = b1[j] + sum_k emb[x[m]][k] * W1[j][k]  (fp32 tile GEMM)
// ---------------------------------------------------------------------------
__global__ __launch_bounds__(256) void px_gemm(
    const int* __restrict__ x, const float* __restrict__ emb,
    const float* __restrict__ W1, const float* __restrict__ b1,
    float* __restrict__ px)
{
  __shared__ float As[8][132];
  __shared__ float Bs[8][132];
  __shared__ int stok[128];
  const int tid = threadIdx.x;
  const int m0 = blockIdx.x * 128;
  const int j0 = blockIdx.y * 128;
  if (tid < 128) stok[tid] = x[m0 + tid];
  __syncthreads();
  const int lr = tid >> 1;
  const int lh = (tid & 1) * 4;
  const int ty = tid >> 4, tx = tid & 15;
  const size_t arow = (size_t)stok[lr] * EMBD;
  const float* brow = W1 + (size_t)(j0 + lr) * (2 * EMBD);

  float acc[8][8];
#pragma unroll
  for (int i = 0; i < 8; i++)
#pragma unroll
    for (int q = 0; q < 8; q++) acc[i][q] = 0.f;

  for (int k0 = 0; k0 < EMBD; k0 += 8) {
    float4 av = *(const float4*)(emb + arow + k0 + lh);
    float4 bv = *(const float4*)(brow + k0 + lh);
    __syncthreads();
    As[lh + 0][lr] = av.x; As[lh + 1][lr] = av.y; As[lh + 2][lr] = av.z; As[lh + 3][lr] = av.w;
    Bs[lh + 0][lr] = bv.x; Bs[lh + 1][lr] = bv.y; Bs[lh + 2][lr] = bv.z; Bs[lh + 3][lr] = bv.w;
    __syncthreads();
#pragma unroll
    for (int kk = 0; kk < 8; kk++) {
      float4 a0 = *(const float4*)&As[kk][ty * 8];
      float4 a1 = *(const float4*)&As[kk][ty * 8 + 4];
      float4 c0 = *(const float4*)&Bs[kk][tx * 8];
      float4 c1 = *(const float4*)&Bs[kk][tx * 8 + 4];
      float a[8] = {a0.x,a0.y,a0.z,a0.w,a1.x,a1.y,a1.z,a1.w};
      float bb[8] = {c0.x,c0.y,c0.z,c0.w,c1.x,c1.y,c1.z,c1.w};
#pragma unroll
      for (int i = 0; i < 8; i++)
#pragma unroll
        for (int q = 0; q < 8; q++)
          acc[i][q] = fmaf(a[i], bb[q], acc[i][q]);
    }
  }
  const float* bp = b1 + j0 + tx * 8;
  float bias0[8];
#pragma unroll
  for (int q = 0; q < 8; q++) bias0[q] = bp[q];
#pragma unroll
  for (int i = 0; i < 8; i++) {
    float o[8];
#pragma unroll
    for (int q = 0; q < 8; q++) o[q] = acc[i][q] + bias0[q];
    float* dst = px + (size_t)(m0 + ty * 8 + i) * HIDD + j0 + tx * 8;
    *(float4*)dst       = make_float4(o[0], o[1], o[2], o[3]);
    *(float4*)(dst + 4) = make_float4(o[4], o[5], o[6], o[7]);
  }
}

// ---------------------------------------------------------------------------
// K2: recurrence v5. 64 wgs x 512 thr (8 waves, waves_per_eu(2) -> 256-reg
// budget). Lane l: qa=l>>4 (k-quarter), jg=l&15. Thread: 4 j x 128 k.
// Weights (64 uint4/thread): kq 0..10 VGPR (44 chunks, 176 regs),
// kq 11..11+NLK-1 in dynamic LDS, rest streamed from L2 (dbuf batches).
// Merge via shfl_xor(16/32); finalize on qa==0 lanes; ONE barrier/step.
// ---------------------------------------------------------------------------
#define DOT4(KQ, W0, W1v, W2v, W3v) do {                                    \
    const uint4 hh = hq[KQ];                                                \
    a0=fdot2((W0).x,hh.x,a0);  a0=fdot2((W0).y,hh.y,a0);                    \
    a0=fdot2((W0).z,hh.z,a0);  a0=fdot2((W0).w,hh.w,a0);                    \
    a1=fdot2((W1v).x,hh.x,a1); a1=fdot2((W1v).y,hh.y,a1);                   \
    a1=fdot2((W1v).z,hh.z,a1); a1=fdot2((W1v).w,hh.w,a1);                   \
    a2=fdot2((W2v).x,hh.x,a2); a2=fdot2((W2v).y,hh.y,a2);                   \
    a2=fdot2((W2v).z,hh.z,a2); a2=fdot2((W2v).w,hh.w,a2);                   \
    a3=fdot2((W3v).x,hh.x,a3); a3=fdot2((W3v).y,hh.y,a3);                   \
    a3=fdot2((W3v).z,hh.z,a3); a3=fdot2((W3v).w,hh.w,a3);                   \
  } while (0)

template<int NLK>
__attribute__((amdgpu_flat_work_group_size(512, 512), amdgpu_waves_per_eu(2)))
__global__ void elman_v5(
    const uint4* __restrict__ wp, const float* __restrict__ px,
    const float* __restrict__ W2, const float* __restrict__ b2,
    float* __restrict__ out)
{
  constexpr int NV  = 44;                 // VGPR chunks (kq 0..10)
  constexpr int KQS = 11 + NLK;           // first streamed kq
  extern __shared__ uint4 wl[];           // NLK*4*512 uint4
  __shared__ unsigned h2[2][256];         // packed fp16 h, double-buffered
  __shared__ float red[2][8];

  const int b   = blockIdx.x;
  const int tid = threadIdx.x;
  const int w   = tid >> 6, l = tid & 63;
  const int qa  = l >> 4, jg = l & 15;

  // prologue: register + LDS weights (all coalesced)
  uint4 wr[NV];
#pragma unroll
  for (int i = 0; i < NV; i++) wr[i] = wp[(size_t)i * 512 + tid];
#pragma unroll
  for (int i = 0; i < 4 * NLK; i++)
    wl[i * 512 + tid] = wp[(size_t)(NV + i) * 512 + tid];
  if (tid < 256) h2[0][tid] = 0u;
  __syncthreads();

  const uint4* ws  = wp + (size_t)(NV + 4 * NLK) * 512 + tid;
  const float* pxb = px + (size_t)b * TT * HIDD;
  float rm0 = -INFINITY, rm1 = -INFINITY, rm2 = -INFINITY, rm3 = -INFINITY;

  for (int t = 0; t < TT; t++) {
    const int cur = t & 1;

    // early issues: px (finalize lanes) + stream batch 0
    float4 pxv = make_float4(0.f, 0.f, 0.f, 0.f);
    if (l < 16)
      pxv = *(const float4*)(pxb + (size_t)t * HIDD + 64 * w + 4 * jg);
    uint4 sa[4], sb[4];
#pragma unroll
    for (int i = 0; i < 4; i++) sa[i] = ws[(size_t)i * 512];

    const uint4* hq = reinterpret_cast<const uint4*>(&h2[cur][0]) + 16 * qa;
    float a0 = 0.f, a1 = 0.f, a2 = 0.f, a3 = 0.f;

    // kq 0..10: VGPR weights (issue stream batch 1 partway)
#pragma unroll
    for (int kq = 0; kq < 11; kq++) {
      DOT4(kq, wr[4 * kq + 0], wr[4 * kq + 1], wr[4 * kq + 2], wr[4 * kq + 3]);
      if (kq == 6) {
#pragma unroll
        for (int i = 0; i < 4; i++) sb[i] = ws[(size_t)(4 + i) * 512];
      }
    }
    // LDS weights
#pragma unroll
    for (int lk = 0; lk < NLK; lk++) {
      const uint4 w0 = wl[(4 * lk + 0) * 512 + tid];
      const uint4 w1 = wl[(4 * lk + 1) * 512 + tid];
      const uint4 w2v = wl[(4 * lk + 2) * 512 + tid];
      const uint4 w3v = wl[(4 * lk + 3) * 512 + tid];
      DOT4(11 + lk, w0, w1, w2v, w3v);
    }
    // streamed kqs: KQS..15, dbuf sa/sb with re-issue
    if constexpr (NLK == 2) {
      DOT4(13, sa[0], sa[1], sa[2], sa[3]);
#pragma unroll
      for (int i = 0; i < 4; i++) sa[i] = ws[(size_t)(8 + i) * 512];
      DOT4(14, sb[0], sb[1], sb[2], sb[3]);
      DOT4(15, sa[0], sa[1], sa[2], sa[3]);
    } else {
      DOT4(12, sa[0], sa[1], sa[2], sa[3]);
#pragma unroll
      for (int i = 0; i < 4; i++) sa[i] = ws[(size_t)(8 + i) * 512];
      DOT4(13, sb[0], sb[1], sb[2], sb[3]);
#pragma unroll
      for (int i = 0; i < 4; i++) sb[i] = ws[(size_t)(12 + i) * 512];
      DOT4(14, sa[0], sa[1], sa[2], sa[3]);
      DOT4(15, sb[0], sb[1], sb[2], sb[3]);
    }

    // merge across the 4 k-quarters (in-wave butterfly)
    a0 += __shfl_xor(a0, 16); a1 += __shfl_xor(a1, 16);
    a2 += __shfl_xor(a2, 16); a3 += __shfl_xor(a3, 16);
    a0 += __shfl_xor(a0, 32); a1 += __shfl_xor(a1, 32);
    a2 += __shfl_xor(a2, 32); a3 += __shfl_xor(a3, 32);

    if (l < 16) {
      float h0 = fast_tanh(a0 + pxv.x);
      float h1 = fast_tanh(a1 + pxv.y);
      float h2n = fast_tanh(a2 + pxv.z);
      float h3 = fast_tanh(a3 + pxv.w);
      rm0 = fmaxf(rm0, h0); rm1 = fmaxf(rm1, h1);
      rm2 = fmaxf(rm2, h2n); rm3 = fmaxf(rm3, h3);
      half2v p01; p01.x = (_Float16)h0; p01.y = (_Float16)h1;
      half2v p23; p23.x = (_Float16)h2n; p23.y = (_Float16)h3;
      *(uint2*)&h2[cur ^ 1][32 * w + 2 * jg] =
          make_uint2(__builtin_bit_cast(unsigned, p01),
                     __builtin_bit_cast(unsigned, p23));
      if (t == TT - 1)
        *(float4*)(out + 2 * BB + (size_t)b * HIDD + 64 * w + 4 * jg) =
            make_float4(h0, h1, h2n, h3);
    }
    __syncthreads();
  }

  // pooled max -> logits (pl overlays the weight LDS; weights are dead now)
  float* pl = (float*)wl;
  if (l < 16)
    *(float4*)&pl[64 * w + 4 * jg] = make_float4(rm0, rm1, rm2, rm3);
  __syncthreads();
  {
    float pv = pl[tid];
    float q0 = pv * W2[tid];
    float q1 = pv * W2[HIDD + tid];
#pragma unroll
    for (int off = 32; off; off >>= 1) {
      q0 += __shfl_down(q0, off);
      q1 += __shfl_down(q1, off);
    }
    const int wv = tid >> 6, ln = tid & 63;
    if (ln == 0) { red[0][wv] = q0; red[1][wv] = q1; }
  }
  __syncthreads();
  if (tid < 2) {
    float s = b2[tid];
#pragma unroll
    for (int i = 0; i < 8; i++) s += red[tid][i];
    out[b * 2 + tid] = s;
  }
}

// ---------------------------------------------------------------------------
extern "C" void kernel_launch(void* const* d_in, const int* in_sizes, int n_in,
                              void* d_out, int out_size, void* d_ws, size_t ws_size,
                              hipStream_t stream)
{
  const int*   x   = (const int*)d_in[0];
  const float* emb = (const float*)d_in[1];
  const float* W1  = (const float*)d_in[2];
  const float* b1  = (const float*)d_in[3];
  const float* W2  = (const float*)d_in[4];
  const float* b2  = (const float*)d_in[5];
  float* out = (float*)d_out;
  char* ws = (char*)d_ws;

  uint4* wp = (uint4*)ws;                        // 512 KB repacked fp16 W1h
  float* px = (float*)(ws + (1 << 19));          // 64 MB
  const size_t need = (size_t)(1 << 19) + (size_t)BB * TT * HIDD * sizeof(float);
  if (ws_size < need) return;

  repack_w1h<<<128, 256, 0, stream>>>(W1, wp);
  {
    dim3 g(TT * BB / 128, HIDD / 128);           // (256, 4)
    px_gemm<<<g, 256, 0, stream>>>(x, emb, W1, b1, px);
  }

  // primary: 8 LDS weight chunks (64 KB dynamic; needs raised cap)
  const size_t dynL = (size_t)8 * 512 * sizeof(uint4);      // 65536
  hipError_t ae = hipFuncSetAttribute(
      reinterpret_cast<const void*>(&elman_v5<2>),
      hipFuncAttributeMaxDynamicSharedMemorySize, (int)dynL);
  if (ae == hipSuccess) {
    elman_v5<2><<<dim3(BB), dim3(512), dynL, stream>>>(wp, px, W2, b2, out);
  } else {
    const size_t dynS = (size_t)4 * 512 * sizeof(uint4);    // 32768
    elman_v5<1><<<dim3(BB), dim3(512), dynS, stream>>>(wp, px, W2, b2, out);
  }
}

// Round 6
// 994.262 us; speedup vs baseline: 1.1256x; 1.1173x over previous
//
#include <hip/hip_runtime.h>
#include <math.h>

#define TT   512
#define BB   64
#define EMBD 512
#define HIDD 512

typedef _Float16 half2v __attribute__((ext_vector_type(2)));

__device__ __forceinline__ float fdot2(unsigned a, unsigned b, float c) {
  half2v av = __builtin_bit_cast(half2v, a);
  half2v bv = __builtin_bit_cast(half2v, b);
#if __has_builtin(__builtin_amdgcn_fdot2)
  return __builtin_amdgcn_fdot2(av, bv, c, false);
#else
  return c + (float)av.x * (float)bv.x + (float)av.y * (float)bv.y;
#endif
}

__device__ __forceinline__ float fast_tanh(float x) {
  float e = __expf(2.0f * x);
  return 1.0f - 2.0f * __builtin_amdgcn_rcpf(e + 1.0f);
}

__device__ __forceinline__ unsigned pack2(float a, float b) {
  half2v hv; hv.x = (_Float16)a; hv.y = (_Float16)b;
  return __builtin_bit_cast(unsigned, hv);
}

// ---------------------------------------------------------------------------
// K0: repack fp32 W1h -> fp16 chunks. elman thread tid: w=tid>>6, l=tid&63,
// qa=l>>4, jg=l&15. chunk c (0..63): jo=c&3, kq=c>>2. Covers
// j=64w+4jg+jo, k=128qa+8kq..+8, packed as 4 dwords of (even,odd) pairs.
// ---------------------------------------------------------------------------
__global__ __launch_bounds__(256) void repack_w1h(
    const float* __restrict__ W1, uint4* __restrict__ wp)
{
  const int gid = blockIdx.x * 256 + threadIdx.x;   // 0..32767
  const int c   = gid >> 9;
  const int tid = gid & 511;
  const int w = tid >> 6, l = tid & 63;
  const int qa = l >> 4, jg = l & 15;
  const int jo = c & 3, kq = c >> 2;
  const int j  = 64 * w + 4 * jg + jo;
  const int k0 = 128 * qa + 8 * kq;
  const float* src = W1 + (size_t)j * (2 * EMBD) + EMBD + k0;
  unsigned r[4];
#pragma unroll
  for (int q = 0; q < 4; q++) r[q] = pack2(src[2 * q], src[2 * q + 1]);
  uint4 u; u.x = r[0]; u.y = r[1]; u.z = r[2]; u.w = r[3];
  wp[gid] = u;
}

// ---------------------------------------------------------------------------
// K1: px[m][j] = b1[j] + sum_k emb[x[m]][k] * W1[j][k]  (fp32 tile GEMM)
// ---------------------------------------------------------------------------
__global__ __launch_bounds__(256) void px_gemm(
    const int* __restrict__ x, const float* __restrict__ emb,
    const float* __restrict__ W1, const float* __restrict__ b1,
    float* __restrict__ px)
{
  __shared__ float As[8][132];
  __shared__ float Bs[8][132];
  __shared__ int stok[128];
  const int tid = threadIdx.x;
  const int m0 = blockIdx.x * 128;
  const int j0 = blockIdx.y * 128;
  if (tid < 128) stok[tid] = x[m0 + tid];
  __syncthreads();
  const int lr = tid >> 1;
  const int lh = (tid & 1) * 4;
  const int ty = tid >> 4, tx = tid & 15;
  const size_t arow = (size_t)stok[lr] * EMBD;
  const float* brow = W1 + (size_t)(j0 + lr) * (2 * EMBD);

  float acc[8][8];
#pragma unroll
  for (int i = 0; i < 8; i++)
#pragma unroll
    for (int q = 0; q < 8; q++) acc[i][q] = 0.f;

  for (int k0 = 0; k0 < EMBD; k0 += 8) {
    float4 av = *(const float4*)(emb + arow + k0 + lh);
    float4 bv = *(const float4*)(brow + k0 + lh);
    __syncthreads();
    As[lh + 0][lr] = av.x; As[lh + 1][lr] = av.y; As[lh + 2][lr] = av.z; As[lh + 3][lr] = av.w;
    Bs[lh + 0][lr] = bv.x; Bs[lh + 1][lr] = bv.y; Bs[lh + 2][lr] = bv.z; Bs[lh + 3][lr] = bv.w;
    __syncthreads();
#pragma unroll
    for (int kk = 0; kk < 8; kk++) {
      float4 a0 = *(const float4*)&As[kk][ty * 8];
      float4 a1 = *(const float4*)&As[kk][ty * 8 + 4];
      float4 c0 = *(const float4*)&Bs[kk][tx * 8];
      float4 c1 = *(const float4*)&Bs[kk][tx * 8 + 4];
      float a[8] = {a0.x,a0.y,a0.z,a0.w,a1.x,a1.y,a1.z,a1.w};
      float bb[8] = {c0.x,c0.y,c0.z,c0.w,c1.x,c1.y,c1.z,c1.w};
#pragma unroll
      for (int i = 0; i < 8; i++)
#pragma unroll
        for (int q = 0; q < 8; q++)
          acc[i][q] = fmaf(a[i], bb[q], acc[i][q]);
    }
  }
  const float* bp = b1 + j0 + tx * 8;
  float bias0[8];
#pragma unroll
  for (int q = 0; q < 8; q++) bias0[q] = bp[q];
#pragma unroll
  for (int i = 0; i < 8; i++) {
    float o[8];
#pragma unroll
    for (int q = 0; q < 8; q++) o[q] = acc[i][q] + bias0[q];
    float* dst = px + (size_t)(m0 + ty * 8 + i) * HIDD + j0 + tx * 8;
    *(float4*)dst       = make_float4(o[0], o[1], o[2], o[3]);
    *(float4*)(dst + 4) = make_float4(o[4], o[5], o[6], o[7]);
  }
}

// ---------------------------------------------------------------------------
// K2: recurrence v6. 64 wgs x 512 thr, 1 wg/CU (130KB LDS forces it).
// Weights: kq 0..11 in 48 reg chunks (192 regs/thread), kq 12 in 32KB
// static LDS, kq 13..12+NDYN in dynamic LDS, (kq 15 streamed iff NDYN==2).
// ZERO per-step L2 streaming in the primary variant.
// h stored as 64 uint4 chunks, physical index p = kq*4 + qa -> the 4
// quarter-groups of a wave read one contiguous 64B line: conflict-free.
// One barrier/step; merge via shfl_xor(16/32).
// ---------------------------------------------------------------------------
#define DOT4(HH, W0, W1v, W2v, W3v) do {                                    \
    const uint4 hh = (HH);                                                  \
    a0=fdot2((W0).x,hh.x,a0);  a0=fdot2((W0).y,hh.y,a0);                    \
    a0=fdot2((W0).z,hh.z,a0);  a0=fdot2((W0).w,hh.w,a0);                    \
    a1=fdot2((W1v).x,hh.x,a1); a1=fdot2((W1v).y,hh.y,a1);                   \
    a1=fdot2((W1v).z,hh.z,a1); a1=fdot2((W1v).w,hh.w,a1);                   \
    a2=fdot2((W2v).x,hh.x,a2); a2=fdot2((W2v).y,hh.y,a2);                   \
    a2=fdot2((W2v).z,hh.z,a2); a2=fdot2((W2v).w,hh.w,a2);                   \
    a3=fdot2((W3v).x,hh.x,a3); a3=fdot2((W3v).y,hh.y,a3);                   \
    a3=fdot2((W3v).z,hh.z,a3); a3=fdot2((W3v).w,hh.w,a3);                   \
  } while (0)

template<int NDYN>   // dynamic-LDS kq groups: 3 (primary) or 2 (fallback)
__attribute__((amdgpu_flat_work_group_size(512, 512), amdgpu_waves_per_eu(2)))
__global__ void elman_v6(
    const uint4* __restrict__ wp, const float* __restrict__ px,
    const float* __restrict__ W2, const float* __restrict__ b2,
    float* __restrict__ out)
{
  extern __shared__ uint4 wdyn[];          // NDYN*4*512 uint4 (32KB each)
  __shared__ uint4 wstat[4 * 512];         // kq 12 (32 KB)
  __shared__ uint4 h2[2][64];              // packed fp16 h, dbuf, p = kq*4+qa
  __shared__ float red[2][8];

  const int b   = blockIdx.x;
  const int tid = threadIdx.x;
  const int w   = tid >> 6, l = tid & 63;
  const int qa  = l >> 4, jg = l & 15;

  // prologue: 48 reg chunks + LDS staging (all coalesced)
  uint4 wr[48];
#pragma unroll
  for (int i = 0; i < 48; i++) wr[i] = wp[(size_t)i * 512 + tid];
#pragma unroll
  for (int i = 0; i < 4; i++) wstat[i * 512 + tid] = wp[(size_t)(48 + i) * 512 + tid];
#pragma unroll
  for (int i = 0; i < 4 * NDYN; i++)
    wdyn[i * 512 + tid] = wp[(size_t)(52 + i) * 512 + tid];
  if (tid < 64) {
    uint4 z; z.x = z.y = z.z = z.w = 0u;
    h2[0][tid] = z;
  }
  __syncthreads();

  const uint4* wsrc = wp + (size_t)60 * 512 + tid;   // kq 15 (fallback stream)
  const float* pxb  = px + (size_t)b * TT * HIDD;
  float rm0 = -INFINITY, rm1 = -INFINITY, rm2 = -INFINITY, rm3 = -INFINITY;

  for (int t = 0; t < TT; t++) {
    const int cur = t & 1;

    // early issues: px (finalize lanes) + streamed kq (fallback only)
    float4 pxv = make_float4(0.f, 0.f, 0.f, 0.f);
    if (l < 16)
      pxv = *(const float4*)(pxb + (size_t)t * HIDD + 64 * w + 4 * jg);
    uint4 sa[4];
    if constexpr (NDYN == 2) {
#pragma unroll
      for (int i = 0; i < 4; i++) sa[i] = wsrc[(size_t)i * 512];
    }

    const uint4* hb = &h2[cur][0];
    float a0 = 0.f, a1 = 0.f, a2 = 0.f, a3 = 0.f;

    // kq 0..11: register weights
#pragma unroll
    for (int kq = 0; kq < 12; kq++)
      DOT4(hb[kq * 4 + qa], wr[4 * kq + 0], wr[4 * kq + 1], wr[4 * kq + 2], wr[4 * kq + 3]);
    // kq 12: static LDS
    DOT4(hb[12 * 4 + qa], wstat[0 * 512 + tid], wstat[1 * 512 + tid],
         wstat[2 * 512 + tid], wstat[3 * 512 + tid]);
    // kq 13..12+NDYN: dynamic LDS
#pragma unroll
    for (int dk = 0; dk < NDYN; dk++)
      DOT4(hb[(13 + dk) * 4 + qa],
           wdyn[(4 * dk + 0) * 512 + tid], wdyn[(4 * dk + 1) * 512 + tid],
           wdyn[(4 * dk + 2) * 512 + tid], wdyn[(4 * dk + 3) * 512 + tid]);
    // kq 15: streamed (fallback only)
    if constexpr (NDYN == 2)
      DOT4(hb[15 * 4 + qa], sa[0], sa[1], sa[2], sa[3]);

    // merge across 4 k-quarters
    a0 += __shfl_xor(a0, 16); a1 += __shfl_xor(a1, 16);
    a2 += __shfl_xor(a2, 16); a3 += __shfl_xor(a3, 16);
    a0 += __shfl_xor(a0, 32); a1 += __shfl_xor(a1, 32);
    a2 += __shfl_xor(a2, 32); a3 += __shfl_xor(a3, 32);

    if (l < 16) {
      float h0 = fast_tanh(a0 + pxv.x);
      float h1 = fast_tanh(a1 + pxv.y);
      float h2n = fast_tanh(a2 + pxv.z);
      float h3 = fast_tanh(a3 + pxv.w);
      rm0 = fmaxf(rm0, h0); rm1 = fmaxf(rm1, h1);
      rm2 = fmaxf(rm2, h2n); rm3 = fmaxf(rm3, h3);
      // write h[j0..j0+3], j0 = 64w+4jg, into p = kqw*4+qw layout
      const int qw  = w >> 1;
      const int kqw = (w & 1) * 8 + (jg >> 1);
      const int di  = (kqw * 4 + qw) * 4 + (jg & 1) * 2;   // dword index
      unsigned* hw = (unsigned*)&h2[cur ^ 1][0];
      *(uint2*)&hw[di] = make_uint2(pack2(h0, h1), pack2(h2n, h3));
      if (t == TT - 1)
        *(float4*)(out + 2 * BB + (size_t)b * HIDD + 64 * w + 4 * jg) =
            make_float4(h0, h1, h2n, h3);
    }
    __syncthreads();
  }

  // pooled max -> logits (pl overlays dynamic weight LDS; weights dead now)
  float* pl = (float*)wdyn;
  if (l < 16)
    *(float4*)&pl[64 * w + 4 * jg] = make_float4(rm0, rm1, rm2, rm3);
  __syncthreads();
  {
    float pv = pl[tid];
    float q0 = pv * W2[tid];
    float q1 = pv * W2[HIDD + tid];
#pragma unroll
    for (int off = 32; off; off >>= 1) {
      q0 += __shfl_down(q0, off);
      q1 += __shfl_down(q1, off);
    }
    const int wv = tid >> 6, ln = tid & 63;
    if (ln == 0) { red[0][wv] = q0; red[1][wv] = q1; }
  }
  __syncthreads();
  if (tid < 2) {
    float s = b2[tid];
#pragma unroll
    for (int i = 0; i < 8; i++) s += red[tid][i];
    out[b * 2 + tid] = s;
  }
}

// ---------------------------------------------------------------------------
extern "C" void kernel_launch(void* const* d_in, const int* in_sizes, int n_in,
                              void* d_out, int out_size, void* d_ws, size_t ws_size,
                              hipStream_t stream)
{
  const int*   x   = (const int*)d_in[0];
  const float* emb = (const float*)d_in[1];
  const float* W1  = (const float*)d_in[2];
  const float* b1  = (const float*)d_in[3];
  const float* W2  = (const float*)d_in[4];
  const float* b2  = (const float*)d_in[5];
  float* out = (float*)d_out;
  char* ws = (char*)d_ws;

  uint4* wp = (uint4*)ws;                        // 512 KB repacked fp16 W1h
  float* px = (float*)(ws + (1 << 19));          // 64 MB
  const size_t need = (size_t)(1 << 19) + (size_t)BB * TT * HIDD * sizeof(float);
  if (ws_size < need) return;

  repack_w1h<<<128, 256, 0, stream>>>(W1, wp);
  {
    dim3 g(TT * BB / 128, HIDD / 128);           // (256, 4)
    px_gemm<<<g, 256, 0, stream>>>(x, emb, W1, b1, px);
  }

  // primary: 3 dynamic kq groups (96 KB dynamic -> attribute required)
  const size_t dynL = (size_t)3 * 4 * 512 * sizeof(uint4);   // 98304
  hipError_t ae = hipFuncSetAttribute(
      reinterpret_cast<const void*>(&elman_v6<3>),
      hipFuncAttributeMaxDynamicSharedMemorySize, (int)dynL);
  if (ae == hipSuccess) {
    elman_v6<3><<<dim3(BB), dim3(512), dynL, stream>>>(wp, px, W2, b2, out);
  } else {
    // fallback: 2 dynamic kq groups (64 KB, default-legal) + 1 streamed kq
    const size_t dynS = (size_t)2 * 4 * 512 * sizeof(uint4); // 65536
    elman_v6<2><<<dim3(BB), dim3(512), dynS, stream>>>(wp, px, W2, b2, out);
  }
}